// Round 1
// baseline (430.978 us; speedup 1.0000x reference)
//
#include <hip/hip_runtime.h>
#include <hip/hip_bf16.h>
#include <math.h>

#define BB 4
#define LL 8192
#define DD 512
#define HH 8
#define MM (BB*LL)      // 32768
#define NQKV 1536
#define S2 32           // L-splits for kv partial reduction

typedef __attribute__((ext_vector_type(4))) float f32x4;
typedef __attribute__((ext_vector_type(8))) short s16x8;
typedef __attribute__((ext_vector_type(4))) short s16x4;

__device__ __forceinline__ float bf2f(short u) {
  union { unsigned int i; float f; } c;
  c.i = ((unsigned int)(unsigned short)u) << 16;
  return c.f;
}
__device__ __forceinline__ short f2bf(float f) {
  union { float f; unsigned int i; } c; c.f = f;
  unsigned int r = c.i + 0x7FFFu + ((c.i >> 16) & 1u);
  return (short)(r >> 16);
}

__device__ __forceinline__ void gload16(const void* g, void* l) {
  __builtin_amdgcn_global_load_lds(
      (const __attribute__((address_space(1))) void*)(g),
      (__attribute__((address_space(3))) void*)(l), 16, 0, 0);
}

// ---------------- conversion kernels ----------------
__global__ void conv_bf16(const float* __restrict__ in, short* __restrict__ out, int n) {
  int i = (blockIdx.x * blockDim.x + threadIdx.x) * 4;
  if (i < n) {
    float4 v = *reinterpret_cast<const float4*>(in + i);
    s16x4 o;
    o[0] = f2bf(v.x); o[1] = f2bf(v.y); o[2] = f2bf(v.z); o[3] = f2bf(v.w);
    *reinterpret_cast<s16x4*>(out + i) = o;
  }
}

// w[K][N] (row-major) -> wt[N][K] bf16
__global__ void conv_wt(const float* __restrict__ w, short* __restrict__ wt, int K, int N) {
  int idx = blockIdx.x * blockDim.x + threadIdx.x;
  if (idx < K * N) {
    int n = idx / K, k = idx - n * K;
    wt[idx] = f2bf(w[(size_t)k * N + n]);
  }
}

// ---------------- bf16 MFMA GEMM, C = A @ BT^T + bias ----------------
// A: [M][KDIM] bf16, BT: [NDIM][KDIM] bf16. 128x128 tile, BK=32, 4 waves.
// MODE 0: epilogue bias + phi(cols<1024) -> bf16 store, stride NDIM (qkv)
// MODE 1: epilogue bias -> fp32 store, stride NDIM (final out)
template<int NDIM, int KDIM, int MODE>
__global__ __launch_bounds__(256, 2)
void gemm_bt(const short* __restrict__ A, const short* __restrict__ BT,
             const float* __restrict__ bias, void* __restrict__ Cout)
{
  __shared__ short As[128 * 32];
  __shared__ short Bs[128 * 32];
  const int tid = threadIdx.x;
  const int wv = tid >> 6, lane = tid & 63;
  const int m0 = blockIdx.x * 128, n0 = blockIdx.y * 128;
  const int wm = (wv >> 1) * 64, wn = (wv & 1) * 64;
  f32x4 acc[4][4] = {};

  for (int k0 = 0; k0 < KDIM; k0 += 32) {
#pragma unroll
    for (int j = 0; j < 2; ++j) {
      const int base = j * 4096 + wv * 1024;   // wave-uniform LDS byte base
      const int off = base + lane * 16;        // per-lane byte offset
      const int r = off >> 6;                  // tile row (0..127)
      const int cc = (off & 63) >> 1;          // bf16 col within 32
      gload16(A  + (size_t)(m0 + r) * KDIM + k0 + cc, (char*)As + base);
      gload16(BT + (size_t)(n0 + r) * KDIM + k0 + cc, (char*)Bs + base);
    }
    __syncthreads();

    const int fr = lane & 15, fk = (lane >> 4) * 8;
    s16x8 af[4], bfg[4];
#pragma unroll
    for (int i = 0; i < 4; ++i) {
      af[i]  = *(const s16x8*)(As + (wm + i * 16 + fr) * 32 + fk);
      bfg[i] = *(const s16x8*)(Bs + (wn + i * 16 + fr) * 32 + fk);
    }
#pragma unroll
    for (int i = 0; i < 4; ++i)
#pragma unroll
      for (int j = 0; j < 4; ++j)
        acc[i][j] = __builtin_amdgcn_mfma_f32_16x16x32_bf16(af[i], bfg[j], acc[i][j], 0, 0, 0);
    __syncthreads();
  }

  // epilogue: C/D layout col = lane&15, row = (lane>>4)*4 + reg
  const int fr = lane & 15, fq = lane >> 4;
#pragma unroll
  for (int j = 0; j < 4; ++j) {
    const int col = n0 + wn + j * 16 + fr;
    const float bv = bias[col];
#pragma unroll
    for (int i = 0; i < 4; ++i) {
      const int rbase = m0 + wm + i * 16 + fq * 4;
#pragma unroll
      for (int r = 0; r < 4; ++r) {
        float v = acc[i][j][r] + bv;
        if (MODE == 0) {
          if (col < 1024) v = (v > 0.f) ? (v + 1.f) : __expf(v);  // phi = elu+1
          ((short*)Cout)[(size_t)(rbase + r) * NDIM + col] = f2bf(v);
        } else {
          ((float*)Cout)[(size_t)(rbase + r) * NDIM + col] = v;
        }
      }
    }
  }
}

// ---------------- kv / ksum partial reduction ----------------
// kv[head][m][d] = sum_l v[l][m] * k[l][d]; per-(head, L-split) partials.
__global__ __launch_bounds__(256, 4)
void kv_partial(const short* __restrict__ qkv_b, float* __restrict__ pkv, float* __restrict__ pks)
{
  const int head = blockIdx.x;   // b*H + h, 0..31
  const int split = blockIdx.y;  // 0..S2-1
  const int b = head >> 3, h = head & 7;
  const int tid = threadIdx.x, wv = tid >> 6, d = tid & 63;
  const short* kb = qkv_b + (size_t)b * LL * NQKV + 512 + h * 64;
  const short* vb = qkv_b + (size_t)b * LL * NQKV + 1024 + h * 64 + wv * 16;
  float acc[16];
#pragma unroll
  for (int j = 0; j < 16; ++j) acc[j] = 0.f;
  float ks = 0.f;
  const int l0 = split * (LL / S2);
  for (int li = 0; li < LL / S2; ++li) {
    const size_t ro = (size_t)(l0 + li) * NQKV;
    const float kd = bf2f(kb[ro + d]);
    ks += kd;
    s16x8 v0 = *(const s16x8*)(vb + ro);
    s16x8 v1 = *(const s16x8*)(vb + ro + 8);
#pragma unroll
    for (int j = 0; j < 8; ++j) acc[j] = fmaf(bf2f(v0[j]), kd, acc[j]);
#pragma unroll
    for (int j = 0; j < 8; ++j) acc[8 + j] = fmaf(bf2f(v1[j]), kd, acc[8 + j]);
  }
  float* o = pkv + ((size_t)head * S2 + split) * 4096 + d;
#pragma unroll
  for (int j = 0; j < 16; ++j) o[(wv * 16 + j) * 64] = acc[j];
  if (wv == 0) pks[((size_t)head * S2 + split) * 64 + d] = ks;
}

__global__ void kv_reduce(const float* __restrict__ pkv, const float* __restrict__ pks,
                          float* __restrict__ kv, float* __restrict__ ksum)
{
  const int idx = blockIdx.x * 256 + threadIdx.x;   // head*4096 + m*64 + d
  const int head = idx >> 12, md = idx & 4095;
  float s = 0.f;
  for (int i = 0; i < S2; ++i) s += pkv[((size_t)head * S2 + i) * 4096 + md];
  kv[idx] = s;
  if (md < 64) {
    float t = 0.f;
    for (int i = 0; i < S2; ++i) t += pks[((size_t)head * S2 + i) * 64 + md];
    ksum[head * 64 + md] = t + 1e-6f;   // fold the +1e-6 here
  }
}

// ---------------- per-row normalize: attn[l][m] = (q_l . kv[m]) / (q_l . ksum) ----------------
__global__ __launch_bounds__(256, 2)
void attn_apply(const short* __restrict__ qkv_b, const float* __restrict__ kv,
                const float* __restrict__ ksum, short* __restrict__ attn)
{
  const int head = blockIdx.x;   // 0..31
  const int split = blockIdx.y;  // 0..15
  const int b = head >> 3, h = head & 7;
  const int tid = threadIdx.x, wv = tid >> 6, lane = tid & 63;

  // per-lane kv row (m = lane) and ksum, held in VGPRs
  float kvr[64], ksr[64];
  const f32x4* kvp = (const f32x4*)(kv + (size_t)head * 4096 + lane * 64);
  const f32x4* ksp = (const f32x4*)(ksum + head * 64);
#pragma unroll
  for (int c = 0; c < 16; ++c) {
    f32x4 t = kvp[c];
    kvr[c * 4 + 0] = t[0]; kvr[c * 4 + 1] = t[1]; kvr[c * 4 + 2] = t[2]; kvr[c * 4 + 3] = t[3];
    f32x4 u = ksp[c];
    ksr[c * 4 + 0] = u[0]; ksr[c * 4 + 1] = u[1]; ksr[c * 4 + 2] = u[2]; ksr[c * 4 + 3] = u[3];
  }

  const short* qb = qkv_b + (size_t)b * LL * NQKV + h * 64;
  short* ob = attn + (size_t)b * LL * DD + h * 64;
  const int l0 = split * 512 + wv * 128;
  for (int li = 0; li < 128; ++li) {
    const int l = l0 + li;
    const s16x8* qp = (const s16x8*)(qb + (size_t)l * NQKV);
    float num = 0.f, den = 0.f;
#pragma unroll
    for (int c = 0; c < 8; ++c) {
      s16x8 t = qp[c];
#pragma unroll
      for (int j = 0; j < 8; ++j) {
        const float qf = bf2f(t[j]);
        num = fmaf(qf, kvr[c * 8 + j], num);
        den = fmaf(qf, ksr[c * 8 + j], den);
      }
    }
    ob[(size_t)l * DD + lane] = f2bf(num / den);
  }
}

// ---------------- launch ----------------
extern "C" void kernel_launch(void* const* d_in, const int* in_sizes, int n_in,
                              void* d_out, int out_size, void* d_ws, size_t ws_size,
                              hipStream_t stream)
{
  const float* x     = (const float*)d_in[0];
  const float* w_qkv = (const float*)d_in[1];
  const float* b_qkv = (const float*)d_in[2];
  const float* w_out = (const float*)d_in[3];
  const float* b_out = (const float*)d_in[4];

  char* ws = (char*)d_ws;
  size_t off = 0;
  short* x_b   = (short*)(ws + off); off += (size_t)MM * DD * 2;        // 32 MB
  short* wq_t  = (short*)(ws + off); off += (size_t)NQKV * DD * 2;      // 1.5 MB
  short* wo_t  = (short*)(ws + off); off += (size_t)DD * DD * 2;        // 0.5 MB
  short* qkv_b = (short*)(ws + off); off += (size_t)MM * NQKV * 2;      // 96 MB
  short* attn_b= (short*)(ws + off); off += (size_t)MM * DD * 2;        // 32 MB
  float* pkv   = (float*)(ws + off); off += (size_t)32 * S2 * 4096 * 4; // 16 MB
  float* pks   = (float*)(ws + off); off += (size_t)32 * S2 * 64 * 4;   // 0.5 MB
  float* kv    = (float*)(ws + off); off += (size_t)32 * 4096 * 4;      // 0.5 MB
  float* ksum  = (float*)(ws + off); off += (size_t)32 * 64 * 4;        // 8 KB

  // 1. convert inputs to bf16 (weights transposed to [N][K])
  conv_bf16<<<dim3((MM * DD / 4 + 255) / 256), dim3(256), 0, stream>>>(x, x_b, MM * DD);
  conv_wt<<<dim3((DD * NQKV + 255) / 256), dim3(256), 0, stream>>>(w_qkv, wq_t, DD, NQKV);
  conv_wt<<<dim3((DD * DD + 255) / 256), dim3(256), 0, stream>>>(w_out, wo_t, DD, DD);

  // 2. qkv = x @ w_qkv + b; phi on q,k; bf16 store
  gemm_bt<NQKV, DD, 0><<<dim3(MM / 128, NQKV / 128), dim3(256), 0, stream>>>(
      x_b, wq_t, b_qkv, (void*)qkv_b);

  // 3. kv / ksum reduction over L
  kv_partial<<<dim3(32, S2), dim3(256), 0, stream>>>(qkv_b, pkv, pks);
  kv_reduce<<<dim3(512), dim3(256), 0, stream>>>(pkv, pks, kv, ksum);

  // 4. per-row normalize
  attn_apply<<<dim3(32, 16), dim3(256), 0, stream>>>(qkv_b, kv, ksum, attn_b);

  // 5. out = attn @ w_out + b_out (fp32)
  gemm_bt<DD, DD, 1><<<dim3(MM / 128, DD / 128), dim3(256), 0, stream>>>(
      attn_b, wo_t, b_out, d_out);
}

// Round 2
// 261.349 us; speedup vs baseline: 1.6490x; 1.6490x over previous
//
#include <hip/hip_runtime.h>
#include <hip/hip_bf16.h>
#include <math.h>

#define BB 4
#define LL 8192
#define DD 512
#define HH 8
#define MM (BB*LL)      // 32768
#define NQKV 1536
#define S2 32           // L-splits for kv partial reduction

typedef __attribute__((ext_vector_type(4))) float f32x4;
typedef __attribute__((ext_vector_type(8))) short s16x8;
typedef __attribute__((ext_vector_type(4))) short s16x4;

__device__ __forceinline__ float bf2f(short u) {
  union { unsigned int i; float f; } c;
  c.i = ((unsigned int)(unsigned short)u) << 16;
  return c.f;
}
__device__ __forceinline__ short f2bf(float f) {
  union { float f; unsigned int i; } c; c.f = f;
  unsigned int r = c.i + 0x7FFFu + ((c.i >> 16) & 1u);
  return (short)(r >> 16);
}

__device__ __forceinline__ void gload16(const void* g, void* l) {
  __builtin_amdgcn_global_load_lds(
      (const __attribute__((address_space(1))) void*)(g),
      (__attribute__((address_space(3))) void*)(l), 16, 0, 0);
}

// ---------------- conversion kernels ----------------
__global__ void conv_bf16(const float* __restrict__ in, short* __restrict__ out, int n) {
  int i = (blockIdx.x * blockDim.x + threadIdx.x) * 4;
  if (i < n) {
    float4 v = *reinterpret_cast<const float4*>(in + i);
    s16x4 o;
    o[0] = f2bf(v.x); o[1] = f2bf(v.y); o[2] = f2bf(v.z); o[3] = f2bf(v.w);
    *reinterpret_cast<s16x4*>(out + i) = o;
  }
}

// w[K][N] (row-major) -> wt[N][K] bf16
__global__ void conv_wt(const float* __restrict__ w, short* __restrict__ wt, int K, int N) {
  int idx = blockIdx.x * blockDim.x + threadIdx.x;
  if (idx < K * N) {
    int n = idx / K, k = idx - n * K;
    wt[idx] = f2bf(w[(size_t)k * N + n]);
  }
}

// ---------------- bf16 MFMA GEMM, C = A @ BT^T + bias ----------------
// A: [M][KDIM] bf16, BT: [NDIM][KDIM] bf16. 128x128 tile, BK=32, 4 waves.
// MODE 0: epilogue bias + phi(cols<1024) -> bf16 store, stride NDIM (qkv)
// MODE 1: epilogue bias -> fp32 store, stride NDIM (final out)
template<int NDIM, int KDIM, int MODE>
__global__ __launch_bounds__(256, 2)
void gemm_bt(const short* __restrict__ A, const short* __restrict__ BT,
             const float* __restrict__ bias, void* __restrict__ Cout)
{
  __shared__ short As[128 * 32];
  __shared__ short Bs[128 * 32];
  const int tid = threadIdx.x;
  const int wv = tid >> 6, lane = tid & 63;
  const int m0 = blockIdx.x * 128, n0 = blockIdx.y * 128;
  const int wm = (wv >> 1) * 64, wn = (wv & 1) * 64;
  f32x4 acc[4][4] = {};

  for (int k0 = 0; k0 < KDIM; k0 += 32) {
#pragma unroll
    for (int j = 0; j < 2; ++j) {
      const int base = j * 4096 + wv * 1024;   // wave-uniform LDS byte base
      const int off = base + lane * 16;        // per-lane byte offset
      const int r = off >> 6;                  // tile row (0..127)
      const int cc = (off & 63) >> 1;          // bf16 col within 32
      gload16(A  + (size_t)(m0 + r) * KDIM + k0 + cc, (char*)As + base);
      gload16(BT + (size_t)(n0 + r) * KDIM + k0 + cc, (char*)Bs + base);
    }
    __syncthreads();

    const int fr = lane & 15, fk = (lane >> 4) * 8;
    s16x8 af[4], bfg[4];
#pragma unroll
    for (int i = 0; i < 4; ++i) {
      af[i]  = *(const s16x8*)(As + (wm + i * 16 + fr) * 32 + fk);
      bfg[i] = *(const s16x8*)(Bs + (wn + i * 16 + fr) * 32 + fk);
    }
#pragma unroll
    for (int i = 0; i < 4; ++i)
#pragma unroll
      for (int j = 0; j < 4; ++j)
        acc[i][j] = __builtin_amdgcn_mfma_f32_16x16x32_bf16(af[i], bfg[j], acc[i][j], 0, 0, 0);
    __syncthreads();
  }

  // epilogue: C/D layout col = lane&15, row = (lane>>4)*4 + reg
  const int fr = lane & 15, fq = lane >> 4;
#pragma unroll
  for (int j = 0; j < 4; ++j) {
    const int col = n0 + wn + j * 16 + fr;
    const float bv = bias[col];
#pragma unroll
    for (int i = 0; i < 4; ++i) {
      const int rbase = m0 + wm + i * 16 + fq * 4;
#pragma unroll
      for (int r = 0; r < 4; ++r) {
        float v = acc[i][j][r] + bv;
        if (MODE == 0) {
          if (col < 1024) v = (v > 0.f) ? (v + 1.f) : __expf(v);  // phi = elu+1
          ((short*)Cout)[(size_t)(rbase + r) * NDIM + col] = f2bf(v);
        } else {
          ((float*)Cout)[(size_t)(rbase + r) * NDIM + col] = v;
        }
      }
    }
  }
}

// ---------------- kv / ksum partial reduction ----------------
// kv[head][m][d] = sum_l v[l][m] * k[l][d]; per-(head, L-split) partials.
__global__ __launch_bounds__(256, 4)
void kv_partial(const short* __restrict__ qkv_b, float* __restrict__ pkv, float* __restrict__ pks)
{
  const int head = blockIdx.x;   // b*H + h, 0..31
  const int split = blockIdx.y;  // 0..S2-1
  const int b = head >> 3, h = head & 7;
  const int tid = threadIdx.x, wv = tid >> 6, d = tid & 63;
  const short* kb = qkv_b + (size_t)b * LL * NQKV + 512 + h * 64;
  const short* vb = qkv_b + (size_t)b * LL * NQKV + 1024 + h * 64 + wv * 16;
  float acc[16];
#pragma unroll
  for (int j = 0; j < 16; ++j) acc[j] = 0.f;
  float ks = 0.f;
  const int l0 = split * (LL / S2);
  for (int li = 0; li < LL / S2; ++li) {
    const size_t ro = (size_t)(l0 + li) * NQKV;
    const float kd = bf2f(kb[ro + d]);
    ks += kd;
    s16x8 v0 = *(const s16x8*)(vb + ro);
    s16x8 v1 = *(const s16x8*)(vb + ro + 8);
#pragma unroll
    for (int j = 0; j < 8; ++j) acc[j] = fmaf(bf2f(v0[j]), kd, acc[j]);
#pragma unroll
    for (int j = 0; j < 8; ++j) acc[8 + j] = fmaf(bf2f(v1[j]), kd, acc[8 + j]);
  }
  float* o = pkv + ((size_t)head * S2 + split) * 4096 + d;
#pragma unroll
  for (int j = 0; j < 16; ++j) o[(wv * 16 + j) * 64] = acc[j];
  if (wv == 0) pks[((size_t)head * S2 + split) * 64 + d] = ks;
}

// reduce partials -> bf16 kv_b [head][m][d], bf16 ksum_b [head][d] (with +1e-6)
__global__ void kv_reduce(const float* __restrict__ pkv, const float* __restrict__ pks,
                          short* __restrict__ kv_b, short* __restrict__ ksum_b)
{
  const int idx = blockIdx.x * 256 + threadIdx.x;   // head*4096 + m*64 + d
  const int head = idx >> 12, md = idx & 4095;
  float s = 0.f;
  for (int i = 0; i < S2; ++i) s += pkv[((size_t)head * S2 + i) * 4096 + md];
  kv_b[idx] = f2bf(s);
  if (md < 64) {
    float t = 0.f;
    for (int i = 0; i < S2; ++i) t += pks[((size_t)head * S2 + i) * 64 + md];
    ksum_b[head * 64 + md] = f2bf(t + 1e-6f);   // fold the +1e-6 here
  }
}

// ---------------- attn via MFMA: attn[l][m] = (q_l . kv[m]) / (q_l . ksum) ----------------
// Per block: one head, 256 rows; 4 waves x 64 rows. M=64/wave, N=64 (+den), K=64.
__global__ __launch_bounds__(256, 2)
void attn_mfma(const short* __restrict__ qkv_b, const short* __restrict__ kv_b,
               const short* __restrict__ ksum_b, short* __restrict__ attn)
{
  const int hb = blockIdx.x;     // 0..31 (b*H + h)
  const int tile = blockIdx.y;   // 0..31 (256 rows each)
  const int b = hb >> 3, h = hb & 7;
  const int tid = threadIdx.x, wv = tid >> 6, lane = tid & 63;
  const int fr = lane & 15, fk = (lane >> 4) * 8;

  // B fragments from kv_b[hb][n][k]: n = j*16+fr, k = kk*32+fk
  const short* kvp = kv_b + (size_t)hb * 4096;
  s16x8 bfrag[4][2];
#pragma unroll
  for (int j = 0; j < 4; ++j)
#pragma unroll
    for (int kk = 0; kk < 2; ++kk)
      bfrag[j][kk] = *(const s16x8*)(kvp + (j * 16 + fr) * 64 + kk * 32 + fk);
  // replicated-ksum B fragment: B[n][k] = ksum[k] for all n -> every out col = den
  s16x8 bden[2];
#pragma unroll
  for (int kk = 0; kk < 2; ++kk)
    bden[kk] = *(const s16x8*)(ksum_b + hb * 64 + kk * 32 + fk);

  const short* qb = qkv_b + (size_t)b * LL * NQKV + h * 64;
  const int l0 = tile * 256 + wv * 64;
  f32x4 accn[4][4] = {};
  f32x4 accd[4] = {};
#pragma unroll
  for (int i = 0; i < 4; ++i) {
#pragma unroll
    for (int kk = 0; kk < 2; ++kk) {
      s16x8 a = *(const s16x8*)(qb + (size_t)(l0 + i * 16 + fr) * NQKV + kk * 32 + fk);
      accd[i] = __builtin_amdgcn_mfma_f32_16x16x32_bf16(a, bden[kk], accd[i], 0, 0, 0);
#pragma unroll
      for (int j = 0; j < 4; ++j)
        accn[i][j] = __builtin_amdgcn_mfma_f32_16x16x32_bf16(a, bfrag[j][kk], accn[i][j], 0, 0, 0);
    }
  }

  // epilogue: col = lane&15, row = (lane>>4)*4 + r
  short* ob = attn + (size_t)b * LL * DD + h * 64;
  const int fq = lane >> 4;
#pragma unroll
  for (int i = 0; i < 4; ++i) {
#pragma unroll
    for (int r = 0; r < 4; ++r) {
      const int row = l0 + i * 16 + fq * 4 + r;
      const float dinv = 1.0f / accd[i][r];
#pragma unroll
      for (int j = 0; j < 4; ++j) {
        ob[(size_t)row * DD + j * 16 + fr] = f2bf(accn[i][j][r] * dinv);
      }
    }
  }
}

// ---------------- launch ----------------
extern "C" void kernel_launch(void* const* d_in, const int* in_sizes, int n_in,
                              void* d_out, int out_size, void* d_ws, size_t ws_size,
                              hipStream_t stream)
{
  const float* x     = (const float*)d_in[0];
  const float* w_qkv = (const float*)d_in[1];
  const float* b_qkv = (const float*)d_in[2];
  const float* w_out = (const float*)d_in[3];
  const float* b_out = (const float*)d_in[4];

  char* ws = (char*)d_ws;
  size_t off = 0;
  short* x_b   = (short*)(ws + off); off += (size_t)MM * DD * 2;        // 32 MB
  short* wq_t  = (short*)(ws + off); off += (size_t)NQKV * DD * 2;      // 1.5 MB
  short* wo_t  = (short*)(ws + off); off += (size_t)DD * DD * 2;        // 0.5 MB
  short* qkv_b = (short*)(ws + off); off += (size_t)MM * NQKV * 2;      // 96 MB
  short* attn_b= (short*)(ws + off); off += (size_t)MM * DD * 2;        // 32 MB
  float* pkv   = (float*)(ws + off); off += (size_t)32 * S2 * 4096 * 4; // 16 MB
  float* pks   = (float*)(ws + off); off += (size_t)32 * S2 * 64 * 4;   // 0.5 MB
  short* kv_b  = (short*)(ws + off); off += (size_t)32 * 4096 * 2;      // 0.25 MB
  short* ksum_b= (short*)(ws + off); off += (size_t)32 * 64 * 2;        // 4 KB

  // 1. convert inputs to bf16 (weights transposed to [N][K])
  conv_bf16<<<dim3((MM * DD / 4 + 255) / 256), dim3(256), 0, stream>>>(x, x_b, MM * DD);
  conv_wt<<<dim3((DD * NQKV + 255) / 256), dim3(256), 0, stream>>>(w_qkv, wq_t, DD, NQKV);
  conv_wt<<<dim3((DD * DD + 255) / 256), dim3(256), 0, stream>>>(w_out, wo_t, DD, DD);

  // 2. qkv = x @ w_qkv + b; phi on q,k; bf16 store
  gemm_bt<NQKV, DD, 0><<<dim3(MM / 128, NQKV / 128), dim3(256), 0, stream>>>(
      x_b, wq_t, b_qkv, (void*)qkv_b);

  // 3. kv / ksum reduction over L
  kv_partial<<<dim3(32, S2), dim3(256), 0, stream>>>(qkv_b, pkv, pks);
  kv_reduce<<<dim3(512), dim3(256), 0, stream>>>(pkv, pks, kv_b, ksum_b);

  // 4. attn = (Q.kv^T) / (Q.ksum) via MFMA
  attn_mfma<<<dim3(32, 32), dim3(256), 0, stream>>>(qkv_b, kv_b, ksum_b, attn_b);

  // 5. out = attn @ w_out + b_out (fp32)
  gemm_bt<DD, DD, 1><<<dim3(MM / 128, DD / 128), dim3(256), 0, stream>>>(
      attn_b, wo_t, b_out, d_out);
}